// Round 1
// baseline (515.465 us; speedup 1.0000x reference)
//
#include <hip/hip_runtime.h>

#define HW 16384
#define Nn 4096

typedef __bf16 bf16x8 __attribute__((ext_vector_type(8)));
typedef unsigned short us8t __attribute__((ext_vector_type(8)));
typedef float f32x4 __attribute__((ext_vector_type(4)));

__device__ __forceinline__ unsigned short f2bf(float f) {
    unsigned int u = __float_as_uint(f);
    u = (u + 0x7fffu + ((u >> 16) & 1u)) >> 16;  // RNE
    return (unsigned short)u;
}
__device__ __forceinline__ float bf2f(unsigned int h) {
    return __uint_as_float(h << 16);
}
__device__ __forceinline__ f32x4 mfma16(us8t a, us8t b, f32x4 c) {
    return __builtin_amdgcn_mfma_f32_16x16x32_bf16(
        __builtin_bit_cast(bf16x8, a), __builtin_bit_cast(bf16x8, b), c, 0, 0, 0);
}

// ---------------- K0: weights -> bf16, transposed [d][c] ----------------
__global__ __launch_bounds__(256) void k_wt(const float* __restrict__ W1,
                                            const float* __restrict__ W2,
                                            const float* __restrict__ Wp,
                                            unsigned short* __restrict__ WT) {
    const int m = blockIdx.x >> 8;     // matrix 0..2
    const int d = blockIdx.x & 255;
    const int c = threadIdx.x;
    const float* W = (m == 0) ? W1 : (m == 1) ? W2 : Wp;
    WT[m * 65536 + d * 256 + c] = f2bf(W[c * 256 + d]);
}

// ---------------- K1: S[b,p,d] = sum_c f[b,c,p] * W1[c,d]  (bf16 out) ----------------
// block: 64 p-rows x 256 d-cols, 256 threads (4 waves, n-split), BK=32
__global__ __launch_bounds__(256) void k_gemm1(const float* __restrict__ f,
                                               const unsigned short* __restrict__ W1T,
                                               unsigned short* __restrict__ S, int b0) {
    __shared__ __align__(16) unsigned short Asb[64][40];  // pitch 80B = 16*5 (odd quad)

    const int blk = blockIdx.x;
    const int bl = blk >> 8;                 // local batch in chunk
    const int b = b0 + bl;
    const int p0 = (blk & 255) << 6;
    const int t = threadIdx.x;
    const int lane = t & 63;
    const int w = t >> 6;
    const int sc = t >> 4;                   // 0..15 (c sub-slot)
    const int sp = (t & 15) << 2;            // p offset 0..60
    const int mrow = lane & 15;
    const int kg = (lane >> 4) << 3;
    const int n0w = w << 6;

    const float* fb = f + ((size_t)b << 22);  // b*256*16384

    f32x4 acc[4][4];
#pragma unroll
    for (int i = 0; i < 4; ++i)
#pragma unroll
        for (int j = 0; j < 4; ++j) acc[i][j] = (f32x4){0.f, 0.f, 0.f, 0.f};

    us8t bnx[4];
#pragma unroll
    for (int nt = 0; nt < 4; ++nt)
        bnx[nt] = *(const us8t*)(W1T + ((n0w + (nt << 4) + mrow) << 8) + kg);

    for (int k0 = 0; k0 < 256; k0 += 32) {
        __syncthreads();
        // stage A-tile (32c x 64p f32) -> LDS transposed bf16 [p][c]
#pragma unroll
        for (int it = 0; it < 2; ++it) {
            const int c = sc + (it << 4);
            const float4 v = *(const float4*)(fb + ((size_t)(k0 + c) << 14) + p0 + sp);
            Asb[sp + 0][c] = f2bf(v.x);
            Asb[sp + 1][c] = f2bf(v.y);
            Asb[sp + 2][c] = f2bf(v.z);
            Asb[sp + 3][c] = f2bf(v.w);
        }
        us8t bcur[4];
#pragma unroll
        for (int nt = 0; nt < 4; ++nt) bcur[nt] = bnx[nt];
        if (k0 < 224) {
#pragma unroll
            for (int nt = 0; nt < 4; ++nt)
                bnx[nt] = *(const us8t*)(W1T + ((n0w + (nt << 4) + mrow) << 8) + k0 + 32 + kg);
        }
        __syncthreads();
        us8t af[4];
#pragma unroll
        for (int mt = 0; mt < 4; ++mt)
            af[mt] = *(const us8t*)&Asb[(mt << 4) + mrow][kg];
#pragma unroll
        for (int mt = 0; mt < 4; ++mt)
#pragma unroll
            for (int nt = 0; nt < 4; ++nt)
                acc[mt][nt] = mfma16(af[mt], bcur[nt], acc[mt][nt]);
    }

    // store S bf16 (C-layout: col=lane&15, row=quad*4+j)
    unsigned short* Sp = S + ((((size_t)bl << 14) + p0) << 8);
    const int r0 = (lane >> 4) << 2;
#pragma unroll
    for (int mt = 0; mt < 4; ++mt)
#pragma unroll
        for (int nt = 0; nt < 4; ++nt) {
            const int col = n0w + (nt << 4) + mrow;
#pragma unroll
            for (int j = 0; j < 4; ++j) {
                const int row = (mt << 4) + r0 + j;
                Sp[((size_t)row << 8) + col] = f2bf(acc[mt][nt][j]);
            }
        }
}

// ---------------- K2: gather+b1+relu -> GEMM2+b2+posenc -> GEMM3+bp -> out ----------------
// block: 64 points x 256 cols, 256 threads (4 waves, n-split)
__global__ __launch_bounds__(256) void k_fused(const unsigned short* __restrict__ S,
                                               const float* __restrict__ verts,
                                               const int* __restrict__ iszp,
                                               const unsigned short* __restrict__ W2T,
                                               const unsigned short* __restrict__ WpT,
                                               const float* __restrict__ b1,
                                               const float* __restrict__ b2,
                                               const float* __restrict__ bpv,
                                               float* __restrict__ out, int b0) {
    __shared__ __align__(16) unsigned short hT[64][264];  // pitch 528B = 16*33 (odd quad)
    __shared__ __align__(16) int pIdx[64][4];
    __shared__ __align__(16) float wBl[64][4];
    __shared__ float vps[64][2];
    __shared__ __align__(16) float b1s[256];
    __shared__ float b2s[256], bps[256];

    const int blk = blockIdx.x;
    const int bl = blk >> 6;
    const int b = b0 + bl;
    const int n0 = (blk & 63) << 6;
    const int t = threadIdx.x;
    const int lane = t & 63;
    const int w = t >> 6;

    b1s[t] = b1[t];
    b2s[t] = b2[t];
    bps[t] = bpv[t];

    if (t < 64) {
        const float isz = (float)iszp[0];
        const size_t vo = ((size_t)b * Nn + n0 + t) << 1;
        const float vx = verts[vo + 0];
        const float vy = verts[vo + 1];
        const float gs = 127.0f / (isz - 1.0f);
        const float ix = fminf(fmaxf(vx * gs, 0.0f), 127.0f);
        const float iy = fminf(fmaxf(vy * gs, 0.0f), 127.0f);
        const float x0 = floorf(ix), y0 = floorf(iy);
        const float wx = ix - x0, wy = iy - y0;
        const int x0i = (int)x0, y0i = (int)y0;
        const int x1i = min(x0i + 1, 127), y1i = min(y0i + 1, 127);
        pIdx[t][0] = (y0i << 7) + x0i;
        pIdx[t][1] = (y0i << 7) + x1i;
        pIdx[t][2] = (y1i << 7) + x0i;
        pIdx[t][3] = (y1i << 7) + x1i;
        wBl[t][0] = (1.0f - wx) * (1.0f - wy);
        wBl[t][1] = wx * (1.0f - wy);
        wBl[t][2] = (1.0f - wx) * wy;
        wBl[t][3] = wx * wy;
        vps[t][0] = vx / isz;
        vps[t][1] = vy / isz;
    }
    __syncthreads();

    // ---- gather (coalesced: 512B bf16 rows) + b1 + relu -> hT ----
    {
        const unsigned short* Sb = S + ((size_t)bl << 22);
        const float4 bl1 = *(const float4*)&b1s[lane << 2];
        for (int i = 0; i < 16; ++i) {
            const int r = (w << 4) + i;
            const int4 pp = *(const int4*)pIdx[r];
            const float4 wt = *(const float4*)wBl[r];
            const uint2 a0 = *(const uint2*)(Sb + ((size_t)pp.x << 8) + (lane << 2));
            const uint2 a1 = *(const uint2*)(Sb + ((size_t)pp.y << 8) + (lane << 2));
            const uint2 a2 = *(const uint2*)(Sb + ((size_t)pp.z << 8) + (lane << 2));
            const uint2 a3 = *(const uint2*)(Sb + ((size_t)pp.w << 8) + (lane << 2));
            float d0 = wt.x * bf2f(a0.x & 0xffffu) + wt.y * bf2f(a1.x & 0xffffu) +
                       wt.z * bf2f(a2.x & 0xffffu) + wt.w * bf2f(a3.x & 0xffffu) + bl1.x;
            float d1 = wt.x * bf2f(a0.x >> 16) + wt.y * bf2f(a1.x >> 16) +
                       wt.z * bf2f(a2.x >> 16) + wt.w * bf2f(a3.x >> 16) + bl1.y;
            float d2 = wt.x * bf2f(a0.y & 0xffffu) + wt.y * bf2f(a1.y & 0xffffu) +
                       wt.z * bf2f(a2.y & 0xffffu) + wt.w * bf2f(a3.y & 0xffffu) + bl1.z;
            float d3 = wt.x * bf2f(a0.y >> 16) + wt.y * bf2f(a1.y >> 16) +
                       wt.z * bf2f(a2.y >> 16) + wt.w * bf2f(a3.y >> 16) + bl1.w;
            d0 = fmaxf(d0, 0.0f);
            d1 = fmaxf(d1, 0.0f);
            d2 = fmaxf(d2, 0.0f);
            d3 = fmaxf(d3, 0.0f);
            uint2 pk;
            pk.x = (unsigned)f2bf(d0) | ((unsigned)f2bf(d1) << 16);
            pk.y = (unsigned)f2bf(d2) | ((unsigned)f2bf(d3) << 16);
            *(uint2*)&hT[r][lane << 2] = pk;
        }
    }
    __syncthreads();

    const int mrow = lane & 15;
    const int kg = (lane >> 4) << 3;
    const int r0 = (lane >> 4) << 2;
    const int n0w = w << 6;

    // ---- GEMM2: vfeat = h @ W2 ----
    f32x4 acc[4][4];
#pragma unroll
    for (int i = 0; i < 4; ++i)
#pragma unroll
        for (int j = 0; j < 4; ++j) acc[i][j] = (f32x4){0.f, 0.f, 0.f, 0.f};

    us8t bnx[4];
#pragma unroll
    for (int nt = 0; nt < 4; ++nt)
        bnx[nt] = *(const us8t*)(W2T + ((n0w + (nt << 4) + mrow) << 8) + kg);
    for (int k0 = 0; k0 < 256; k0 += 32) {
        us8t bcur[4];
#pragma unroll
        for (int nt = 0; nt < 4; ++nt) bcur[nt] = bnx[nt];
        if (k0 < 224) {
#pragma unroll
            for (int nt = 0; nt < 4; ++nt)
                bnx[nt] = *(const us8t*)(W2T + ((n0w + (nt << 4) + mrow) << 8) + k0 + 32 + kg);
        }
        us8t af[4];
#pragma unroll
        for (int mt = 0; mt < 4; ++mt)
            af[mt] = *(const us8t*)&hT[(mt << 4) + mrow][k0 + kg];
#pragma unroll
        for (int mt = 0; mt < 4; ++mt)
#pragma unroll
            for (int nt = 0; nt < 4; ++nt)
                acc[mt][nt] = mfma16(af[mt], bcur[nt], acc[mt][nt]);
    }
    __syncthreads();  // all hT reads done before overwrite

    // ---- epilogue: g = vfeat + b2 + posenc -> hT (bf16) ----
    const float C2 = -0.20762050593046f;  // -log2(10000)/64
#pragma unroll
    for (int nt = 0; nt < 4; ++nt) {
        const int col = n0w + (nt << 4) + mrow;
        const float bias2 = b2s[col];
        const int ci = col & 127;
        const float dv = exp2f((float)(ci >> 1) * C2) * 1000.0f;
        const int sel = col >> 7;  // 0 -> x, 1 -> y
#pragma unroll
        for (int mt = 0; mt < 4; ++mt)
#pragma unroll
            for (int j = 0; j < 4; ++j) {
                const int row = (mt << 4) + r0 + j;
                const float ang = vps[row][sel] * dv;
                const float pe = (col & 1) ? __cosf(ang) : __sinf(ang);
                hT[row][col] = f2bf(acc[mt][nt][j] + bias2 + pe);
            }
    }
    __syncthreads();

    // ---- GEMM3: out = g @ Wp + bp ----
#pragma unroll
    for (int i = 0; i < 4; ++i)
#pragma unroll
        for (int j = 0; j < 4; ++j) acc[i][j] = (f32x4){0.f, 0.f, 0.f, 0.f};
#pragma unroll
    for (int nt = 0; nt < 4; ++nt)
        bnx[nt] = *(const us8t*)(WpT + ((n0w + (nt << 4) + mrow) << 8) + kg);
    for (int k0 = 0; k0 < 256; k0 += 32) {
        us8t bcur[4];
#pragma unroll
        for (int nt = 0; nt < 4; ++nt) bcur[nt] = bnx[nt];
        if (k0 < 224) {
#pragma unroll
            for (int nt = 0; nt < 4; ++nt)
                bnx[nt] = *(const us8t*)(WpT + ((n0w + (nt << 4) + mrow) << 8) + k0 + 32 + kg);
        }
        us8t af[4];
#pragma unroll
        for (int mt = 0; mt < 4; ++mt)
            af[mt] = *(const us8t*)&hT[(mt << 4) + mrow][k0 + kg];
#pragma unroll
        for (int mt = 0; mt < 4; ++mt)
#pragma unroll
            for (int nt = 0; nt < 4; ++nt)
                acc[mt][nt] = mfma16(af[mt], bcur[nt], acc[mt][nt]);
    }

    float* ob = out + (((size_t)b * Nn + n0) << 8);
#pragma unroll
    for (int nt = 0; nt < 4; ++nt) {
        const int col = n0w + (nt << 4) + mrow;
        const float bb = bps[col];
#pragma unroll
        for (int mt = 0; mt < 4; ++mt)
#pragma unroll
            for (int j = 0; j < 4; ++j) {
                const int row = (mt << 4) + r0 + j;
                ob[((size_t)row << 8) + col] = acc[mt][nt][j] + bb;
            }
    }
}

extern "C" void kernel_launch(void* const* d_in, const int* in_sizes, int n_in,
                              void* d_out, int out_size, void* d_ws, size_t ws_size,
                              hipStream_t stream) {
    const float* f = (const float*)d_in[0];
    const float* verts = (const float*)d_in[1];
    const int* isz = (const int*)d_in[2];
    const float* W1 = (const float*)d_in[3];
    const float* b1 = (const float*)d_in[4];
    const float* W2 = (const float*)d_in[5];
    const float* b2 = (const float*)d_in[6];
    const float* Wp = (const float*)d_in[7];
    const float* bp = (const float*)d_in[8];
    float* out = (float*)d_out;

    unsigned short* WT = (unsigned short*)d_ws;                       // 3 x 128KB bf16 transposed
    const size_t S_OFF = 512u << 10;
    unsigned short* S = (unsigned short*)((char*)d_ws + S_OFF);

    const size_t perBatch = (size_t)HW * 256 * 2;  // 8 MB bf16
    size_t sbytes = (ws_size > S_OFF) ? (ws_size - S_OFF) : 0;
    int nbMax = (int)(sbytes / perBatch);
    if (nbMax < 1) nbMax = 1;
    if (nbMax > 16) nbMax = 16;

    k_wt<<<dim3(768), dim3(256), 0, stream>>>(W1, W2, Wp, WT);
    for (int b0 = 0; b0 < 16; b0 += nbMax) {
        const int nb = (16 - b0 < nbMax) ? (16 - b0) : nbMax;
        k_gemm1<<<dim3(nb * 256), dim3(256), 0, stream>>>(f, WT, S, b0);
        k_fused<<<dim3(nb * 64), dim3(256), 0, stream>>>(S, verts, isz, WT + 65536, WT + 131072,
                                                         b1, b2, bp, out, b0);
    }
}